// Round 8
// baseline (115.206 us; speedup 1.0000x reference)
//
#include <hip/hip_runtime.h>
#include <hip/hip_bf16.h>
#include <hip/hip_fp16.h>
#include <stdint.h>

// Problem constants
#define BATCH 256
#define NPOS 49
#define CCH 128
#define KWIN 7
#define HEADS 4
#define K2 49
#define HD 32
#define MROWS (BATCH * NPOS)         // 12544
#define QSCALE 0.17677669529663687f  // 32^-0.5

using short8 = __attribute__((ext_vector_type(8))) short;
using floatx4 = __attribute__((ext_vector_type(4))) float;

static __device__ inline short f2bf(float x) {
  uint32_t u = __float_as_uint(x);
  uint32_t r = (u + 0x7fffu + ((u >> 16) & 1u)) >> 16;
  return (short)r;
}

// ---------------------------------------------------------------------------
// bf16 MFMA GEMM (unchanged): C[M x N] = A[M x 128] @ W^T + bias
// ---------------------------------------------------------------------------
template <int MODE>
__global__ __launch_bounds__(256) void dwa_gemm(
    const float* __restrict__ A, const float* __restrict__ W0,
    const float* __restrict__ W1, const float* __restrict__ bias0,
    const float* __restrict__ bias1, float* __restrict__ out0,
    float* __restrict__ out1) {
  __shared__ short Abs[64][128];
  __shared__ short Bbs[64][128];
  const int tid = threadIdx.x;
  const int m0 = blockIdx.x * 64;
  const int n0 = blockIdx.y * 64;

#pragma unroll
  for (int p = 0; p < 4; ++p) {
    int c = tid + p * 256;
    int row = c >> 4;
    int slot = c & 15;
    const float* src = A + (size_t)(m0 + row) * 128 + slot * 8;
    float4 f0 = *(const float4*)(src);
    float4 f1 = *(const float4*)(src + 4);
    short8 pk;
    pk[0] = f2bf(f0.x); pk[1] = f2bf(f0.y); pk[2] = f2bf(f0.z); pk[3] = f2bf(f0.w);
    pk[4] = f2bf(f1.x); pk[5] = f2bf(f1.y); pk[6] = f2bf(f1.z); pk[7] = f2bf(f1.w);
    *(short8*)&Abs[row][(slot ^ (row & 7)) * 8] = pk;
  }
#pragma unroll
  for (int p = 0; p < 4; ++p) {
    int c = tid + p * 256;
    int row = c >> 4;
    int slot = c & 15;
    int colg = n0 + row;
    float4 f0 = make_float4(0.f, 0.f, 0.f, 0.f), f1 = f0;
    if (MODE == 1 || colg < 384) {
      const float* src = W0 + (size_t)colg * 128 + slot * 8;
      f0 = *(const float4*)(src);
      f1 = *(const float4*)(src + 4);
    } else if (colg < 776) {
      const float* src = W1 + (size_t)(colg - 384) * 128 + slot * 8;
      f0 = *(const float4*)(src);
      f1 = *(const float4*)(src + 4);
    }
    short8 pk;
    pk[0] = f2bf(f0.x); pk[1] = f2bf(f0.y); pk[2] = f2bf(f0.z); pk[3] = f2bf(f0.w);
    pk[4] = f2bf(f1.x); pk[5] = f2bf(f1.y); pk[6] = f2bf(f1.z); pk[7] = f2bf(f1.w);
    *(short8*)&Bbs[row][(slot ^ (row & 7)) * 8] = pk;
  }
  __syncthreads();

  const int lane = tid & 63;
  const int wv = tid >> 6;
  const int wrow = (wv >> 1) * 32;
  const int wcol = (wv & 1) * 32;
  const int lr = lane & 15;
  const int lg = lane >> 4;

  floatx4 acc[2][2];
#pragma unroll
  for (int i = 0; i < 2; ++i)
#pragma unroll
    for (int j = 0; j < 2; ++j) acc[i][j] = {0.f, 0.f, 0.f, 0.f};

#pragma unroll
  for (int ks = 0; ks < 4; ++ks) {
    short8 af[2], bf[2];
#pragma unroll
    for (int i = 0; i < 2; ++i) {
      int r = wrow + i * 16 + lr;
      int slot = (ks * 4 + lg) ^ (r & 7);
      af[i] = *(const short8*)&Abs[r][slot * 8];
    }
#pragma unroll
    for (int j = 0; j < 2; ++j) {
      int r = wcol + j * 16 + lr;
      int slot = (ks * 4 + lg) ^ (r & 7);
      bf[j] = *(const short8*)&Bbs[r][slot * 8];
    }
#pragma unroll
    for (int i = 0; i < 2; ++i)
#pragma unroll
      for (int j = 0; j < 2; ++j)
        acc[i][j] = __builtin_amdgcn_mfma_f32_16x16x32_bf16(af[i], bf[j],
                                                            acc[i][j], 0, 0, 0);
  }

#pragma unroll
  for (int i = 0; i < 2; ++i) {
#pragma unroll
    for (int reg = 0; reg < 4; ++reg) {
      int grow = m0 + wrow + i * 16 + lg * 4 + reg;
#pragma unroll
      for (int j = 0; j < 2; ++j) {
        int gcol = n0 + wcol + j * 16 + lr;
        float v = acc[i][j][reg];
        if (MODE == 1) {
          out0[(size_t)grow * 128 + gcol] = v + bias0[gcol];
        } else {
          if (gcol < 384) {
            float sc = (gcol < 128) ? QSCALE : 1.0f;
            out0[(size_t)grow * 384 + gcol] = (v + bias0[gcol]) * sc;
          } else if (gcol < 776) {
            out1[(size_t)grow * 392 + (gcol - 384)] = v + bias1[gcol - 384];
          }
        }
      }
    }
  }
}

// ---------------------------------------------------------------------------
// Wave-synchronous deformable window attention. One block per (b,h),
// 256 threads = 4 waves. Only TWO barriers:
//   [prefetch offsets to regs] stage q,k(bf16),v(f32)  -- BARRIER --
//   S0 = q@k^T via MFMA (wave w -> rows 16w..16w+15)   -- BARRIER --
//   then PER WAVE on its exclusive row strip {0-12|13-24|25-36|37-48}:
//     zero A2 strip -> scores (n wave-uniform per slot, k2=lane) -> exp ->
//     scatter pe*w into A2 (+pe into ones-col 49) -> lgkmcnt(0) ->
//     AV: out[n][d] = (A2[n][:]@v[:,d]) / A2[n][49]   (v hoisted to 49 VGPRs)
// A2 (fp32, 49x52) aliases the dead q/k bf16 staging. LDS ~27.5 KB.
// ---------------------------------------------------------------------------
__global__ __launch_bounds__(256, 4) void dwa_attn(
    const float* __restrict__ qkv_buf, const float* __restrict__ off_buf,
    const float* __restrict__ rpb, float* __restrict__ attn_out) {
  __shared__ __align__(16) char uQK[20480];       // qbs+kbs bf16; later A2 f32
  __shared__ __align__(16) float S0[49 * 52];     // q@k^T
  __shared__ __align__(16) float vsh[49][36];     // v rows fp32

  short* qbs = (short*)uQK;       // [64*40] bf16
  short* kbs = qbs + 64 * 40;     // [64*40] bf16
  float* A2 = (float*)uQK;        // [49*52] fp32 (aliases qbs/kbs)

  // XCD-aware swizzle: 1024 blocks = 8 XCDs x 128; 4 heads of a b adjacent.
  const int bid = blockIdx.x;
  const int swz = (bid & 7) * 128 + (bid >> 3);
  const int b = swz >> 2;
  const int h = swz & 3;
  const int tid = threadIdx.x;
  const int lane = tid & 63;
  const int wv = tid >> 6;

  // per-wave row strip
  const int rbase = (wv == 0) ? 0 : 1 + 12 * wv;   // 0,13,25,37
  const int rcnt = (wv == 0) ? 13 : 12;
  const int rhi = rbase + rcnt - 1;

  // ---- offset prefetch (consumed after 2 barriers) ----
  const float* offp = off_buf + (size_t)(b * 49) * 392 + h * 98;
  float2 offr[13];
#pragma unroll
  for (int s = 0; s < 13; ++s) {
    if (s < rcnt && lane < 49)
      offr[s] = *(const float2*)(offp + (size_t)(rbase + s) * 392 + lane * 2);
  }
  // per-lane k2 constants
  const int kk2 = (lane < 49) ? lane : 48;
  const int ky = kk2 / 7;
  const int kx = kk2 - ky * 7;
  const float bias_r = rpb[h * 169 + (ky + 3) * 13 + (kx + 3)];

  // ---- stage q,k (bf16) and v (f32) ----
  {
    int r = tid >> 2;
    int c4 = tid & 3;
    if (r < 49) {
      const float* base = qkv_buf + (size_t)(b * 49 + r) * 384 + h * 32 + c4 * 8;
      float4 q0 = *(const float4*)(base);
      float4 q1 = *(const float4*)(base + 4);
      float4 k0 = *(const float4*)(base + 128);
      float4 k1 = *(const float4*)(base + 132);
      short8 qp, kp;
      qp[0] = f2bf(q0.x); qp[1] = f2bf(q0.y); qp[2] = f2bf(q0.z); qp[3] = f2bf(q0.w);
      qp[4] = f2bf(q1.x); qp[5] = f2bf(q1.y); qp[6] = f2bf(q1.z); qp[7] = f2bf(q1.w);
      kp[0] = f2bf(k0.x); kp[1] = f2bf(k0.y); kp[2] = f2bf(k0.z); kp[3] = f2bf(k0.w);
      kp[4] = f2bf(k1.x); kp[5] = f2bf(k1.y); kp[6] = f2bf(k1.z); kp[7] = f2bf(k1.w);
      *(short8*)&qbs[r * 40 + c4 * 8] = qp;
      *(short8*)&kbs[r * 40 + c4 * 8] = kp;
    } else {
      short8 zz = {0, 0, 0, 0, 0, 0, 0, 0};
      *(short8*)&qbs[r * 40 + c4 * 8] = zz;
      *(short8*)&kbs[r * 40 + c4 * 8] = zz;
    }
    const float* vbase = qkv_buf + (size_t)(b * 49) * 384 + 256 + h * 32;
    for (int i4 = tid; i4 < 392; i4 += 256) {
      int n = i4 >> 3;
      int d4 = (i4 & 7) << 2;
      *(float4*)&vsh[n][d4] = *(const float4*)(vbase + n * 384 + d4);
    }
  }
  __syncthreads();  // barrier 1

  // ---- S0 = q @ k^T : wave w computes rows 16w..16w+15, cols 0..48 ----
  {
    const int lr = lane & 15;
    const int lg = lane >> 4;
    short8 af = *(const short8*)&qbs[(wv * 16 + lr) * 40 + lg * 8];
    floatx4 z = {0.f, 0.f, 0.f, 0.f};
#pragma unroll
    for (int j = 0; j < 4; ++j) {
      short8 bf = *(const short8*)&kbs[(j * 16 + lr) * 40 + lg * 8];
      floatx4 c = __builtin_amdgcn_mfma_f32_16x16x32_bf16(af, bf, z, 0, 0, 0);
      int gcol = j * 16 + lr;
#pragma unroll
      for (int reg = 0; reg < 4; ++reg) {
        int grow = wv * 16 + lg * 4 + reg;
        if (grow < 49 && gcol < 49) S0[grow * 52 + gcol] = c[reg];
      }
    }
  }
  __syncthreads();  // barrier 2 -- q/k region now dead, reusable as A2

  // ---- zero this wave's A2 strip (rows rbase..rhi, 52 cols) ----
  {
    float4 z4 = make_float4(0.f, 0.f, 0.f, 0.f);
    const int b13 = rbase * 13;          // 52 floats = 13 float4 per row
    const int e13 = (rhi + 1) * 13;
    for (int i = b13 + lane; i < e13; i += 64) ((float4*)A2)[i] = z4;
  }

  // ---- scores + exp + unnormalized scatter (wave-local rows) ----
#pragma unroll
  for (int s = 0; s < 13; ++s) {
    if (s < rcnt && lane < 49) {
      int n = rbase + s;
      unsigned int nu = (unsigned)n;
      int iy = (int)(nu / 7u), ix = n - iy * 7;
      float py = fminf(fmaxf((float)(iy + ky - 3) + offr[s].x, 0.f), 6.f);
      float px = fminf(fmaxf((float)(ix + kx - 3) + offr[s].y, 0.f), 6.f);
      float y0f = floorf(py), x0f = floorf(px);
      float wy = py - y0f, wx = px - x0f;
      int y0 = (int)y0f, x0 = (int)x0f;
      int y1 = min(y0 + 1, 6), x1 = min(x0 + 1, 6);
      const float* srow = &S0[n * 52];
      float* arow = A2 + n * 52;
      int i00 = y0 * 7 + x0, i01 = y0 * 7 + x1;
      int i10 = y1 * 7 + x0, i11 = y1 * 7 + x1;
      float w00 = (1.f - wy) * (1.f - wx);
      float w01 = (1.f - wy) * wx;
      float w10 = wy * (1.f - wx);
      float w11 = wy * wx;
      float sc = w00 * srow[i00] + w01 * srow[i01] + w10 * srow[i10] +
                 w11 * srow[i11] + bias_r;
      float pe = __expf(sc);  // no max-sub: scores ~N(0,1), exp-safe
      atomicAdd(arow + i00, pe * w00);
      atomicAdd(arow + i01, pe * w01);
      atomicAdd(arow + i10, pe * w10);
      atomicAdd(arow + i11, pe * w11);
      atomicAdd(arow + 49, pe);  // ones-column: rowsum for free
    }
  }
  // wave-local handoff: all DS atomics of THIS wave complete before reads
  asm volatile("s_waitcnt lgkmcnt(0)" ::: "memory");
  __builtin_amdgcn_sched_barrier(0);

  // ---- AV: out[n][d] = (A2[n][0..48] . v[0..48][d]) / A2[n][49] ----
  {
    const int dd = lane & 31;
    const int half = lane >> 5;
    float vreg[49];
#pragma unroll
    for (int m = 0; m < 49; ++m) vreg[m] = vsh[m][dd];
#pragma unroll
    for (int s = 0; s < 7; ++s) {
      int n = rbase + 2 * s + half;
      if (n <= rhi) {
        const float* arow = A2 + n * 52;
        float o = 0.f;
#pragma unroll
        for (int m = 0; m < 48; m += 4) {
          float4 a4 = *(const float4*)(arow + m);
          o = fmaf(a4.x, vreg[m + 0], o);
          o = fmaf(a4.y, vreg[m + 1], o);
          o = fmaf(a4.z, vreg[m + 2], o);
          o = fmaf(a4.w, vreg[m + 3], o);
        }
        float2 tail = *(const float2*)(arow + 48);  // {A2[48], rowsum}
        o = fmaf(tail.x, vreg[48], o);
        attn_out[(size_t)(b * 49 + n) * 128 + h * 32 + dd] =
            o * (1.f / tail.y);
      }
    }
  }
}

// ---------------------------------------------------------------------------
extern "C" void kernel_launch(void* const* d_in, const int* in_sizes, int n_in,
                              void* d_out, int out_size, void* d_ws,
                              size_t ws_size, hipStream_t stream) {
  const float* x = (const float*)d_in[0];
  const float* w_qkv = (const float*)d_in[1];
  const float* b_qkv = (const float*)d_in[2];
  const float* w_off = (const float*)d_in[3];
  const float* b_off = (const float*)d_in[4];
  const float* rpb = (const float*)d_in[5];
  const float* w_proj = (const float*)d_in[6];
  const float* b_proj = (const float*)d_in[7];
  float* out = (float*)d_out;

  float* ws = (float*)d_ws;
  float* qkv_buf = ws;                              // 12544*384
  float* off_buf = qkv_buf + (size_t)MROWS * 384;   // 12544*392
  float* attn_out = off_buf + (size_t)MROWS * 392;  // 12544*128

  dwa_gemm<0><<<dim3(196, 13), 256, 0, stream>>>(x, w_qkv, w_off, b_qkv, b_off,
                                                 qkv_buf, off_buf);
  dwa_attn<<<BATCH * HEADS, 256, 0, stream>>>(qkv_buf, off_buf, rpb, attn_out);
  dwa_gemm<1><<<dim3(196, 2), 256, 0, stream>>>(attn_out, w_proj, nullptr,
                                                b_proj, nullptr, out, nullptr);
}

// Round 10
// 110.482 us; speedup vs baseline: 1.0428x; 1.0428x over previous
//
#include <hip/hip_runtime.h>
#include <hip/hip_bf16.h>
#include <hip/hip_fp16.h>
#include <stdint.h>

// Problem constants
#define BATCH 256
#define NPOS 49
#define CCH 128
#define KWIN 7
#define HEADS 4
#define K2 49
#define HD 32
#define MROWS (BATCH * NPOS)         // 12544
#define QSCALE 0.17677669529663687f  // 32^-0.5

using short8 = __attribute__((ext_vector_type(8))) short;
using floatx4 = __attribute__((ext_vector_type(4))) float;

static __device__ inline short f2bf(float x) {
  uint32_t u = __float_as_uint(x);
  uint32_t r = (u + 0x7fffu + ((u >> 16) & 1u)) >> 16;
  return (short)r;
}

// ---------------------------------------------------------------------------
// bf16 MFMA GEMM (unchanged): C[M x N] = A[M x 128] @ W^T + bias
// ---------------------------------------------------------------------------
template <int MODE>
__global__ __launch_bounds__(256) void dwa_gemm(
    const float* __restrict__ A, const float* __restrict__ W0,
    const float* __restrict__ W1, const float* __restrict__ bias0,
    const float* __restrict__ bias1, float* __restrict__ out0,
    float* __restrict__ out1) {
  __shared__ short Abs[64][128];
  __shared__ short Bbs[64][128];
  const int tid = threadIdx.x;
  const int m0 = blockIdx.x * 64;
  const int n0 = blockIdx.y * 64;

#pragma unroll
  for (int p = 0; p < 4; ++p) {
    int c = tid + p * 256;
    int row = c >> 4;
    int slot = c & 15;
    const float* src = A + (size_t)(m0 + row) * 128 + slot * 8;
    float4 f0 = *(const float4*)(src);
    float4 f1 = *(const float4*)(src + 4);
    short8 pk;
    pk[0] = f2bf(f0.x); pk[1] = f2bf(f0.y); pk[2] = f2bf(f0.z); pk[3] = f2bf(f0.w);
    pk[4] = f2bf(f1.x); pk[5] = f2bf(f1.y); pk[6] = f2bf(f1.z); pk[7] = f2bf(f1.w);
    *(short8*)&Abs[row][(slot ^ (row & 7)) * 8] = pk;
  }
#pragma unroll
  for (int p = 0; p < 4; ++p) {
    int c = tid + p * 256;
    int row = c >> 4;
    int slot = c & 15;
    int colg = n0 + row;
    float4 f0 = make_float4(0.f, 0.f, 0.f, 0.f), f1 = f0;
    if (MODE == 1 || colg < 384) {
      const float* src = W0 + (size_t)colg * 128 + slot * 8;
      f0 = *(const float4*)(src);
      f1 = *(const float4*)(src + 4);
    } else if (colg < 776) {
      const float* src = W1 + (size_t)(colg - 384) * 128 + slot * 8;
      f0 = *(const float4*)(src);
      f1 = *(const float4*)(src + 4);
    }
    short8 pk;
    pk[0] = f2bf(f0.x); pk[1] = f2bf(f0.y); pk[2] = f2bf(f0.z); pk[3] = f2bf(f0.w);
    pk[4] = f2bf(f1.x); pk[5] = f2bf(f1.y); pk[6] = f2bf(f1.z); pk[7] = f2bf(f1.w);
    *(short8*)&Bbs[row][(slot ^ (row & 7)) * 8] = pk;
  }
  __syncthreads();

  const int lane = tid & 63;
  const int wv = tid >> 6;
  const int wrow = (wv >> 1) * 32;
  const int wcol = (wv & 1) * 32;
  const int lr = lane & 15;
  const int lg = lane >> 4;

  floatx4 acc[2][2];
#pragma unroll
  for (int i = 0; i < 2; ++i)
#pragma unroll
    for (int j = 0; j < 2; ++j) acc[i][j] = {0.f, 0.f, 0.f, 0.f};

#pragma unroll
  for (int ks = 0; ks < 4; ++ks) {
    short8 af[2], bf[2];
#pragma unroll
    for (int i = 0; i < 2; ++i) {
      int r = wrow + i * 16 + lr;
      int slot = (ks * 4 + lg) ^ (r & 7);
      af[i] = *(const short8*)&Abs[r][slot * 8];
    }
#pragma unroll
    for (int j = 0; j < 2; ++j) {
      int r = wcol + j * 16 + lr;
      int slot = (ks * 4 + lg) ^ (r & 7);
      bf[j] = *(const short8*)&Bbs[r][slot * 8];
    }
#pragma unroll
    for (int i = 0; i < 2; ++i)
#pragma unroll
      for (int j = 0; j < 2; ++j)
        acc[i][j] = __builtin_amdgcn_mfma_f32_16x16x32_bf16(af[i], bf[j],
                                                            acc[i][j], 0, 0, 0);
  }

#pragma unroll
  for (int i = 0; i < 2; ++i) {
#pragma unroll
    for (int reg = 0; reg < 4; ++reg) {
      int grow = m0 + wrow + i * 16 + lg * 4 + reg;
#pragma unroll
      for (int j = 0; j < 2; ++j) {
        int gcol = n0 + wcol + j * 16 + lr;
        float v = acc[i][j][reg];
        if (MODE == 1) {
          out0[(size_t)grow * 128 + gcol] = v + bias0[gcol];
        } else {
          if (gcol < 384) {
            float sc = (gcol < 128) ? QSCALE : 1.0f;
            out0[(size_t)grow * 384 + gcol] = (v + bias0[gcol]) * sc;
          } else if (gcol < 776) {
            out1[(size_t)grow * 392 + (gcol - 384)] = v + bias1[gcol - 384];
          }
        }
      }
    }
  }
}

// ---------------------------------------------------------------------------
// Deformable window attention, LDS-instruction-minimized.
// One block per (b,h), 512 threads = 8 waves, 4 barriers.
//  P1 stage: q,k->bf16 [64][40] (rows 49-63 zero); v->bf16 TRANSPOSED
//     vbT[d][m] (cols 49-63 zero for ALL 32 d rows -- r9 bug was zeroing
//     only d=0..15, leaving stale LDS (possible bf16 NaN/Inf) in the MFMA
//     k-sum); zero A2f; prefetch off+bias to regs.
//  P2 S0 = k@q^T via MFMA(A=k,B=q): C[m][n], lane's 4 regs = 4 consecutive
//     m at fixed n -> ds_write_b128 into row-major S0[n][m] (wide!).
//  P3 scores: gather = {base,base+1,base+7,base+8} unconditionally (clamped
//     neighbors have exactly-zero weights); exp (no max-sub, |s|<~6);
//     scatter unnormalized pe*w via 4 LDS atomics + ones-col(49) rowsum.
//  P4 cvt: A2f (f32) -> A2b (bf16, [64][72], aliases dead q/k staging).
//  P5 AV via MFMA: out[n][d] = (A2b[n][:] . vbT[d][:]) / A2f[n][49].
//     (A2b cols 52..63 garbage x vbT zeros = 0; rows 49-63 discarded.)
// LDS ~34.5 KB -> 4 blocks/CU = 32 waves/CU.
// ---------------------------------------------------------------------------
__global__ __launch_bounds__(512, 8) void dwa_attn(
    const float* __restrict__ qkv_buf, const float* __restrict__ off_buf,
    const float* __restrict__ rpb, float* __restrict__ attn_out) {
  __shared__ __align__(16) char uQK[10240];     // qbs+kbs bf16; later A2b
  __shared__ __align__(16) float S0[2564];      // [49][52] + 16 zero tail
  __shared__ __align__(16) float A2f[2564];     // [49][52] + 16 (col49=rowsum)
  __shared__ __align__(16) short vbT[32 * 72];  // bf16 v^T: [d][m], pitch 72

  short* qbs = (short*)uQK;      // [64][40] bf16
  short* kbs = qbs + 64 * 40;    // [64][40] bf16
  short* A2b = (short*)uQK;      // [64][72] bf16 (9216B, aliases qbs/kbs)

  // XCD swizzle: 4 heads of one b adjacent on an XCD
  const int bid = blockIdx.x;
  const int swz = (bid & 7) * 128 + (bid >> 3);
  const int b = swz >> 2;
  const int h = swz & 3;
  const int tid = threadIdx.x;

  // ---- prefetch offsets + bias for my 5 score-slots (regs) ----
  const float* offp = off_buf + (size_t)(b * 49) * 392 + h * 98;
  float2 offr[5];
  float biasr[5];
#pragma unroll
  for (int p = 0; p < 5; ++p) {
    if (p < 4 || tid < 353) {  // 2401 = 4*512 + 353
      int e = tid + p * 512;
      unsigned nu = (unsigned)e / 49u;
      int k2 = e - (int)nu * 49;
      unsigned ku = (unsigned)k2;
      int ky = (int)(ku / 7u), kx = k2 - ky * 7;
      offr[p] = *(const float2*)(offp + (size_t)nu * 392 + k2 * 2);
      biasr[p] = rpb[h * 169 + (ky + 3) * 13 + (kx + 3)];
    }
  }

  // ---- P1 stage ----
  if (tid < 256) {
    // q/k rows 0..63 (rows >=49 zeroed), bf16, pitch 40
    int r = tid >> 2;
    int c4 = tid & 3;
    if (r < 49) {
      const float* base = qkv_buf + (size_t)(b * 49 + r) * 384 + h * 32 + c4 * 8;
      float4 q0 = *(const float4*)(base);
      float4 q1 = *(const float4*)(base + 4);
      float4 k0 = *(const float4*)(base + 128);
      float4 k1 = *(const float4*)(base + 132);
      short8 qp, kp;
      qp[0] = f2bf(q0.x); qp[1] = f2bf(q0.y); qp[2] = f2bf(q0.z); qp[3] = f2bf(q0.w);
      qp[4] = f2bf(q1.x); qp[5] = f2bf(q1.y); qp[6] = f2bf(q1.z); qp[7] = f2bf(q1.w);
      kp[0] = f2bf(k0.x); kp[1] = f2bf(k0.y); kp[2] = f2bf(k0.z); kp[3] = f2bf(k0.w);
      kp[4] = f2bf(k1.x); kp[5] = f2bf(k1.y); kp[6] = f2bf(k1.z); kp[7] = f2bf(k1.w);
      *(short8*)&qbs[r * 40 + c4 * 8] = qp;
      *(short8*)&kbs[r * 40 + c4 * 8] = kp;
    } else {
      short8 zz = {0, 0, 0, 0, 0, 0, 0, 0};
      *(short8*)&qbs[r * 40 + c4 * 8] = zz;
      *(short8*)&kbs[r * 40 + c4 * 8] = zz;
    }
    // zero A2f (incl tail): 641 float4 chunks
    float4 z4 = make_float4(0.f, 0.f, 0.f, 0.f);
#pragma unroll
    for (int it = 0; it < 3; ++it) {
      int i = tid + it * 256;
      if (i < 641) ((float4*)A2f)[i] = z4;
    }
    if (tid < 4) *(float4*)&S0[2548 + tid * 4] = z4;  // S0 zero tail
  } else {
    int t2 = tid - 256;
    // v -> vbT[d][n] (bf16), coalesced global reads (lanes over d)
    const float* vbase = qkv_buf + (size_t)(b * 49) * 384 + 256 + h * 32;
#pragma unroll
    for (int it = 0; it < 7; ++it) {
      int i = t2 + it * 256;
      if (i < 1568) {  // 49*32
        int n = i >> 5;
        int d = i & 31;
        vbT[d * 72 + n] = f2bf(vbase[(size_t)n * 384 + d]);
      }
    }
    // zero vbT cols 49..63 for ALL 32 d rows (32*15 = 480 entries)
    for (int i = t2; i < 480; i += 256) {
      int d = i / 15;
      int j = i - d * 15;
      vbT[d * 72 + 49 + j] = 0;
    }
  }
  __syncthreads();  // B1

  const int lane = tid & 63;
  const int wv = tid >> 6;  // 0..7
  const int lr = lane & 15;
  const int lg = lane >> 4;

  // ---- P2: S0[n][m] = k_m . q_n via mfma(A=k, B=q), wide b128 writes ----
  {
    const int nt = wv >> 1;          // n-tile 0..3
    const int mt2 = (wv & 1) * 2;    // m-tiles {mt2, mt2+1}
    const int n = nt * 16 + lr;
    short8 bf = *(const short8*)&qbs[n * 40 + lg * 8];
    floatx4 z = {0.f, 0.f, 0.f, 0.f};
#pragma unroll
    for (int t = 0; t < 2; ++t) {
      const int mt = mt2 + t;
      short8 af = *(const short8*)&kbs[(mt * 16 + lr) * 40 + lg * 8];
      floatx4 c = __builtin_amdgcn_mfma_f32_16x16x32_bf16(af, bf, z, 0, 0, 0);
      int mbase = mt * 16 + lg * 4;
      if (mbase < 52 && n < 49) {
        *(float4*)&S0[n * 52 + mbase] =
            make_float4(c[0], c[1], c[2], c[3]);
      }
    }
  }
  __syncthreads();  // B2 (q/k staging dead after this)

  // ---- P3: scores + exp + unnormalized scatter ----
#pragma unroll
  for (int p = 0; p < 5; ++p) {
    if (p < 4 || tid < 353) {
      int e = tid + p * 512;
      unsigned nu = (unsigned)e / 49u;
      int n = (int)nu;
      int k2 = e - n * 49;
      int iy = (int)(nu / 7u), ix = n - iy * 7;
      unsigned ku = (unsigned)k2;
      int ky = (int)(ku / 7u), kx = k2 - ky * 7;
      float py = fminf(fmaxf((float)(iy + ky - 3) + offr[p].x, 0.f), 6.f);
      float px = fminf(fmaxf((float)(ix + kx - 3) + offr[p].y, 0.f), 6.f);
      float y0f = floorf(py), x0f = floorf(px);
      float wy = py - y0f, wx = px - x0f;
      int base = n * 52 + (int)y0f * 7 + (int)x0f;
      // clamped neighbors have exactly-zero weights -> unconditional addrs
      float s00 = S0[base], s01 = S0[base + 1];
      float s10 = S0[base + 7], s11 = S0[base + 8];
      float w00 = (1.f - wy) * (1.f - wx);
      float w01 = (1.f - wy) * wx;
      float w10 = wy * (1.f - wx);
      float w11 = wy * wx;
      float s = w00 * s00 + w01 * s01 + w10 * s10 + w11 * s11 + biasr[p];
      float pe = __expf(s);  // |s| <~ 6: exp-safe without max-sub
      atomicAdd(&A2f[base], pe * w00);
      atomicAdd(&A2f[base + 1], pe * w01);
      atomicAdd(&A2f[base + 7], pe * w10);
      atomicAdd(&A2f[base + 8], pe * w11);
      atomicAdd(&A2f[n * 52 + 49], pe);  // ones-column rowsum
    }
  }
  __syncthreads();  // B3

  // ---- P4: convert A2f -> A2b bf16 [64][72] (aliases q/k region) ----
  if (tid < 392) {  // 49 rows x 8 chunks of 8
    int n = tid >> 3;
    int j8 = tid & 7;
    const float* src = &A2f[n * 52 + j8 * 8];  // j8>=6 reads stray f32s;
    float4 f0 = *(const float4*)(src);          // killed by vbT zero cols
    float4 f1 = *(const float4*)(src + 4);
    short8 pk;
    pk[0] = f2bf(f0.x); pk[1] = f2bf(f0.y); pk[2] = f2bf(f0.z); pk[3] = f2bf(f0.w);
    pk[4] = f2bf(f1.x); pk[5] = f2bf(f1.y); pk[6] = f2bf(f1.z); pk[7] = f2bf(f1.w);
    *(short8*)&A2b[n * 72 + j8 * 8] = pk;
  }
  __syncthreads();  // B4

  // ---- P5: out[n][d] = (A2b[n] . vbT[d]) / rowsum[n] via MFMA ----
  {
    const int nt = wv >> 1;        // n-tile 0..3
    const int dt = wv & 1;         // d-tile 0..1
    floatx4 acc = {0.f, 0.f, 0.f, 0.f};
#pragma unroll
    for (int ks = 0; ks < 2; ++ks) {
      short8 af = *(const short8*)&A2b[(nt * 16 + lr) * 72 + ks * 32 + lg * 8];
      short8 bf = *(const short8*)&vbT[(dt * 16 + lr) * 72 + ks * 32 + lg * 8];
      acc = __builtin_amdgcn_mfma_f32_16x16x32_bf16(af, bf, acc, 0, 0, 0);
    }
    const int d = dt * 16 + lr;
#pragma unroll
    for (int reg = 0; reg < 4; ++reg) {
      int n = nt * 16 + lg * 4 + reg;
      if (n < 49) {
        float inv = 1.f / A2f[n * 52 + 49];
        attn_out[(size_t)(b * 49 + n) * 128 + h * 32 + d] = acc[reg] * inv;
      }
    }
  }
}

// ---------------------------------------------------------------------------
extern "C" void kernel_launch(void* const* d_in, const int* in_sizes, int n_in,
                              void* d_out, int out_size, void* d_ws,
                              size_t ws_size, hipStream_t stream) {
  const float* x = (const float*)d_in[0];
  const float* w_qkv = (const float*)d_in[1];
  const float* b_qkv = (const float*)d_in[2];
  const float* w_off = (const float*)d_in[3];
  const float* b_off = (const float*)d_in[4];
  const float* rpb = (const float*)d_in[5];
  const float* w_proj = (const float*)d_in[6];
  const float* b_proj = (const float*)d_in[7];
  float* out = (float*)d_out;

  float* ws = (float*)d_ws;
  float* qkv_buf = ws;                              // 12544*384
  float* off_buf = qkv_buf + (size_t)MROWS * 384;   // 12544*392
  float* attn_out = off_buf + (size_t)MROWS * 392;  // 12544*128

  dwa_gemm<0><<<dim3(196, 13), 256, 0, stream>>>(x, w_qkv, w_off, b_qkv, b_off,
                                                 qkv_buf, off_buf);
  dwa_attn<<<BATCH * HEADS, 512, 0, stream>>>(qkv_buf, off_buf, rpb, attn_out);
  dwa_gemm<1><<<dim3(196, 2), 256, 0, stream>>>(attn_out, w_proj, nullptr,
                                                b_proj, nullptr, out, nullptr);
}

// Round 11
// 94.649 us; speedup vs baseline: 1.2172x; 1.1673x over previous
//
#include <hip/hip_runtime.h>
#include <hip/hip_bf16.h>
#include <hip/hip_fp16.h>
#include <stdint.h>

// Problem constants
#define BATCH 256
#define NPOS 49
#define CCH 128
#define KWIN 7
#define HEADS 4
#define K2 49
#define HD 32
#define MROWS (BATCH * NPOS)         // 12544
#define QSCALE 0.17677669529663687f  // 32^-0.5

using short8 = __attribute__((ext_vector_type(8))) short;
using floatx4 = __attribute__((ext_vector_type(4))) float;

static __device__ inline short f2bf(float x) {
  uint32_t u = __float_as_uint(x);
  uint32_t r = (u + 0x7fffu + ((u >> 16) & 1u)) >> 16;
  return (short)r;
}

// ---------------------------------------------------------------------------
// bf16 MFMA GEMM: C[M x N] = A[M x 128] @ W^T + bias
// MODE 1 additionally scales A rows per 32-col head-group by 1/rs[row][head]
// (normalization folded out of the attention kernel; row-scaling commutes
// with right-multiplication by W^T).
// ---------------------------------------------------------------------------
template <int MODE>
__global__ __launch_bounds__(256) void dwa_gemm(
    const float* __restrict__ A, const float* __restrict__ W0,
    const float* __restrict__ W1, const float* __restrict__ bias0,
    const float* __restrict__ bias1, float* __restrict__ out0,
    float* __restrict__ out1, const float* __restrict__ rs) {
  __shared__ short Abs[64][128];
  __shared__ short Bbs[64][128];
  const int tid = threadIdx.x;
  const int m0 = blockIdx.x * 64;
  const int n0 = blockIdx.y * 64;

#pragma unroll
  for (int p = 0; p < 4; ++p) {
    int c = tid + p * 256;
    int row = c >> 4;
    int slot = c & 15;
    const float* src = A + (size_t)(m0 + row) * 128 + slot * 8;
    float4 f0 = *(const float4*)(src);
    float4 f1 = *(const float4*)(src + 4);
    if (MODE == 1) {
      float irs = 1.0f / rs[(size_t)(m0 + row) * 4 + (slot >> 2)];
      f0.x *= irs; f0.y *= irs; f0.z *= irs; f0.w *= irs;
      f1.x *= irs; f1.y *= irs; f1.z *= irs; f1.w *= irs;
    }
    short8 pk;
    pk[0] = f2bf(f0.x); pk[1] = f2bf(f0.y); pk[2] = f2bf(f0.z); pk[3] = f2bf(f0.w);
    pk[4] = f2bf(f1.x); pk[5] = f2bf(f1.y); pk[6] = f2bf(f1.z); pk[7] = f2bf(f1.w);
    *(short8*)&Abs[row][(slot ^ (row & 7)) * 8] = pk;
  }
#pragma unroll
  for (int p = 0; p < 4; ++p) {
    int c = tid + p * 256;
    int row = c >> 4;
    int slot = c & 15;
    int colg = n0 + row;
    float4 f0 = make_float4(0.f, 0.f, 0.f, 0.f), f1 = f0;
    if (MODE == 1 || colg < 384) {
      const float* src = W0 + (size_t)colg * 128 + slot * 8;
      f0 = *(const float4*)(src);
      f1 = *(const float4*)(src + 4);
    } else if (colg < 776) {
      const float* src = W1 + (size_t)(colg - 384) * 128 + slot * 8;
      f0 = *(const float4*)(src);
      f1 = *(const float4*)(src + 4);
    }
    short8 pk;
    pk[0] = f2bf(f0.x); pk[1] = f2bf(f0.y); pk[2] = f2bf(f0.z); pk[3] = f2bf(f0.w);
    pk[4] = f2bf(f1.x); pk[5] = f2bf(f1.y); pk[6] = f2bf(f1.z); pk[7] = f2bf(f1.w);
    *(short8*)&Bbs[row][(slot ^ (row & 7)) * 8] = pk;
  }
  __syncthreads();

  const int lane = tid & 63;
  const int wv = tid >> 6;
  const int wrow = (wv >> 1) * 32;
  const int wcol = (wv & 1) * 32;
  const int lr = lane & 15;
  const int lg = lane >> 4;

  floatx4 acc[2][2];
#pragma unroll
  for (int i = 0; i < 2; ++i)
#pragma unroll
    for (int j = 0; j < 2; ++j) acc[i][j] = {0.f, 0.f, 0.f, 0.f};

#pragma unroll
  for (int ks = 0; ks < 4; ++ks) {
    short8 af[2], bf[2];
#pragma unroll
    for (int i = 0; i < 2; ++i) {
      int r = wrow + i * 16 + lr;
      int slot = (ks * 4 + lg) ^ (r & 7);
      af[i] = *(const short8*)&Abs[r][slot * 8];
    }
#pragma unroll
    for (int j = 0; j < 2; ++j) {
      int r = wcol + j * 16 + lr;
      int slot = (ks * 4 + lg) ^ (r & 7);
      bf[j] = *(const short8*)&Bbs[r][slot * 8];
    }
#pragma unroll
    for (int i = 0; i < 2; ++i)
#pragma unroll
      for (int j = 0; j < 2; ++j)
        acc[i][j] = __builtin_amdgcn_mfma_f32_16x16x32_bf16(af[i], bf[j],
                                                            acc[i][j], 0, 0, 0);
  }

#pragma unroll
  for (int i = 0; i < 2; ++i) {
#pragma unroll
    for (int reg = 0; reg < 4; ++reg) {
      int grow = m0 + wrow + i * 16 + lg * 4 + reg;
#pragma unroll
      for (int j = 0; j < 2; ++j) {
        int gcol = n0 + wcol + j * 16 + lr;
        float v = acc[i][j][reg];
        if (MODE == 1) {
          out0[(size_t)grow * 128 + gcol] = v + bias0[gcol];
        } else {
          if (gcol < 384) {
            float sc = (gcol < 128) ? QSCALE : 1.0f;
            out0[(size_t)grow * 384 + gcol] = (v + bias0[gcol]) * sc;
          } else if (gcol < 776) {
            out1[(size_t)grow * 392 + (gcol - 384)] = v + bias1[gcol - 384];
          }
        }
      }
    }
  }
}

// ---------------------------------------------------------------------------
// Deformable window attention. One block per (b,h), 512 threads = 8 waves,
// 4 barriers. vs r10: NO rowsum ones-column atomics (the 49-way same-address
// LDS-atomic serialization). Rowsum computed in P5 via an extra MFMA with an
// in-register ones-B fragment (col 0 = ones); P4 zero-masks A2b cols 48+ so
// the ones-sum is exact. Output written UNNORMALIZED + rs_buf[row][head];
// normalization folded into dwa_gemm<1> A-staging.
// ---------------------------------------------------------------------------
__global__ __launch_bounds__(512, 8) void dwa_attn(
    const float* __restrict__ qkv_buf, const float* __restrict__ off_buf,
    const float* __restrict__ rpb, float* __restrict__ attn_out,
    float* __restrict__ rs_buf) {
  __shared__ __align__(16) char uQK[10240];     // qbs+kbs bf16; later A2b
  __shared__ __align__(16) float S0[2564];      // [49][52] + 16 zero tail
  __shared__ __align__(16) float A2f[2564];     // [49][52] + 16
  __shared__ __align__(16) short vbT[32 * 72];  // bf16 v^T: [d][m], pitch 72

  short* qbs = (short*)uQK;      // [64][40] bf16
  short* kbs = qbs + 64 * 40;    // [64][40] bf16
  short* A2b = (short*)uQK;      // [64][72] bf16 (aliases qbs/kbs)

  // XCD swizzle: 4 heads of one b adjacent on an XCD
  const int bid = blockIdx.x;
  const int swz = (bid & 7) * 128 + (bid >> 3);
  const int b = swz >> 2;
  const int h = swz & 3;
  const int tid = threadIdx.x;

  // ---- prefetch offsets + bias for my 5 score-slots (regs) ----
  const float* offp = off_buf + (size_t)(b * 49) * 392 + h * 98;
  float2 offr[5];
  float biasr[5];
#pragma unroll
  for (int p = 0; p < 5; ++p) {
    if (p < 4 || tid < 353) {  // 2401 = 4*512 + 353
      int e = tid + p * 512;
      unsigned nu = (unsigned)e / 49u;
      int k2 = e - (int)nu * 49;
      unsigned ku = (unsigned)k2;
      int ky = (int)(ku / 7u), kx = k2 - ky * 7;
      offr[p] = *(const float2*)(offp + (size_t)nu * 392 + k2 * 2);
      biasr[p] = rpb[h * 169 + (ky + 3) * 13 + (kx + 3)];
    }
  }

  // ---- P1 stage ----
  if (tid < 256) {
    int r = tid >> 2;
    int c4 = tid & 3;
    if (r < 49) {
      const float* base = qkv_buf + (size_t)(b * 49 + r) * 384 + h * 32 + c4 * 8;
      float4 q0 = *(const float4*)(base);
      float4 q1 = *(const float4*)(base + 4);
      float4 k0 = *(const float4*)(base + 128);
      float4 k1 = *(const float4*)(base + 132);
      short8 qp, kp;
      qp[0] = f2bf(q0.x); qp[1] = f2bf(q0.y); qp[2] = f2bf(q0.z); qp[3] = f2bf(q0.w);
      qp[4] = f2bf(q1.x); qp[5] = f2bf(q1.y); qp[6] = f2bf(q1.z); qp[7] = f2bf(q1.w);
      kp[0] = f2bf(k0.x); kp[1] = f2bf(k0.y); kp[2] = f2bf(k0.z); kp[3] = f2bf(k0.w);
      kp[4] = f2bf(k1.x); kp[5] = f2bf(k1.y); kp[6] = f2bf(k1.z); kp[7] = f2bf(k1.w);
      *(short8*)&qbs[r * 40 + c4 * 8] = qp;
      *(short8*)&kbs[r * 40 + c4 * 8] = kp;
    } else {
      short8 zz = {0, 0, 0, 0, 0, 0, 0, 0};
      *(short8*)&qbs[r * 40 + c4 * 8] = zz;
      *(short8*)&kbs[r * 40 + c4 * 8] = zz;
    }
    float4 z4 = make_float4(0.f, 0.f, 0.f, 0.f);
#pragma unroll
    for (int it = 0; it < 3; ++it) {
      int i = tid + it * 256;
      if (i < 641) ((float4*)A2f)[i] = z4;
    }
    if (tid < 4) *(float4*)&S0[2548 + tid * 4] = z4;  // S0 zero tail
  } else {
    int t2 = tid - 256;
    const float* vbase = qkv_buf + (size_t)(b * 49) * 384 + 256 + h * 32;
#pragma unroll
    for (int it = 0; it < 7; ++it) {
      int i = t2 + it * 256;
      if (i < 1568) {  // 49*32
        int n = i >> 5;
        int d = i & 31;
        vbT[d * 72 + n] = f2bf(vbase[(size_t)n * 384 + d]);
      }
    }
    // zero vbT cols 49..63 for ALL 32 d rows (32*15 = 480 entries)
    for (int i = t2; i < 480; i += 256) {
      int d = i / 15;
      int j = i - d * 15;
      vbT[d * 72 + 49 + j] = 0;
    }
  }
  __syncthreads();  // B1

  const int lane = tid & 63;
  const int wv = tid >> 6;  // 0..7
  const int lr = lane & 15;
  const int lg = lane >> 4;

  // ---- P2: S0[n][m] = k_m . q_n via mfma(A=k, B=q), wide b128 writes ----
  {
    const int nt = wv >> 1;          // n-tile 0..3
    const int mt2 = (wv & 1) * 2;    // m-tiles {mt2, mt2+1}
    const int n = nt * 16 + lr;
    short8 bf = *(const short8*)&qbs[n * 40 + lg * 8];
    floatx4 z = {0.f, 0.f, 0.f, 0.f};
#pragma unroll
    for (int t = 0; t < 2; ++t) {
      const int mt = mt2 + t;
      short8 af = *(const short8*)&kbs[(mt * 16 + lr) * 40 + lg * 8];
      floatx4 c = __builtin_amdgcn_mfma_f32_16x16x32_bf16(af, bf, z, 0, 0, 0);
      int mbase = mt * 16 + lg * 4;
      if (mbase < 52 && n < 49) {
        *(float4*)&S0[n * 52 + mbase] =
            make_float4(c[0], c[1], c[2], c[3]);
      }
    }
  }
  __syncthreads();  // B2 (q/k staging dead after this)

  // ---- P3: scores + exp + unnormalized scatter (4 atomics/slot only) ----
#pragma unroll
  for (int p = 0; p < 5; ++p) {
    if (p < 4 || tid < 353) {
      int e = tid + p * 512;
      unsigned nu = (unsigned)e / 49u;
      int n = (int)nu;
      int k2 = e - n * 49;
      int iy = (int)(nu / 7u), ix = n - iy * 7;
      unsigned ku = (unsigned)k2;
      int ky = (int)(ku / 7u), kx = k2 - ky * 7;
      float py = fminf(fmaxf((float)(iy + ky - 3) + offr[p].x, 0.f), 6.f);
      float px = fminf(fmaxf((float)(ix + kx - 3) + offr[p].y, 0.f), 6.f);
      float y0f = floorf(py), x0f = floorf(px);
      float wy = py - y0f, wx = px - x0f;
      int base = n * 52 + (int)y0f * 7 + (int)x0f;
      float s00 = S0[base], s01 = S0[base + 1];
      float s10 = S0[base + 7], s11 = S0[base + 8];
      float w00 = (1.f - wy) * (1.f - wx);
      float w01 = (1.f - wy) * wx;
      float w10 = wy * (1.f - wx);
      float w11 = wy * wx;
      float s = w00 * s00 + w01 * s01 + w10 * s10 + w11 * s11 + biasr[p];
      float pe = __expf(s);  // |s| <~ 6: exp-safe without max-sub
      atomicAdd(&A2f[base], pe * w00);
      atomicAdd(&A2f[base + 1], pe * w01);
      atomicAdd(&A2f[base + 7], pe * w10);
      atomicAdd(&A2f[base + 8], pe * w11);
    }
  }
  __syncthreads();  // B3

  // ---- P4: A2f -> A2b bf16 [64][72], cols 48..63 masked {A2[48],0,...} ----
  if (tid < 392) {  // 49 rows x 8 chunks of 8
    int n = tid >> 3;
    int j8 = tid & 7;
    short8 pk = {0, 0, 0, 0, 0, 0, 0, 0};
    if (j8 < 6) {
      const float* src = &A2f[n * 52 + j8 * 8];
      float4 f0 = *(const float4*)(src);
      float4 f1 = *(const float4*)(src + 4);
      pk[0] = f2bf(f0.x); pk[1] = f2bf(f0.y); pk[2] = f2bf(f0.z); pk[3] = f2bf(f0.w);
      pk[4] = f2bf(f1.x); pk[5] = f2bf(f1.y); pk[6] = f2bf(f1.z); pk[7] = f2bf(f1.w);
    } else if (j8 == 6) {
      // cols 48..55: {A2[48], 0(49), 0(50), 0(51), 0, 0, 0, 0}
      float4 f0 = *(const float4*)&A2f[n * 52 + 48];
      pk[0] = f2bf(f0.x); pk[1] = f2bf(f0.y); pk[2] = f2bf(f0.z); pk[3] = f2bf(f0.w);
    }  // j8 == 7: cols 56..63 all zero
    *(short8*)&A2b[n * 72 + j8 * 8] = pk;
  }
  __syncthreads();  // B4

  // ---- P5: out[n][d] = A2b[n] . vbT[d] (unnormalized) + rowsum MFMA ----
  {
    const int nt = wv >> 1;        // n-tile 0..3
    const int dt = wv & 1;         // d-tile 0..1
    floatx4 acc = {0.f, 0.f, 0.f, 0.f};
    floatx4 accS = {0.f, 0.f, 0.f, 0.f};
    short8 bones;
#pragma unroll
    for (int u = 0; u < 8; ++u) bones[u] = (lr == 0) ? (short)0x3F80 : (short)0;
#pragma unroll
    for (int ks = 0; ks < 2; ++ks) {
      short8 af = *(const short8*)&A2b[(nt * 16 + lr) * 72 + ks * 32 + lg * 8];
      short8 bf = *(const short8*)&vbT[(dt * 16 + lr) * 72 + ks * 32 + lg * 8];
      acc = __builtin_amdgcn_mfma_f32_16x16x32_bf16(af, bf, acc, 0, 0, 0);
      if (dt == 0)
        accS = __builtin_amdgcn_mfma_f32_16x16x32_bf16(af, bones, accS, 0, 0, 0);
    }
    const int d = dt * 16 + lr;
#pragma unroll
    for (int reg = 0; reg < 4; ++reg) {
      int n = nt * 16 + lg * 4 + reg;
      if (n < 49) {
        attn_out[(size_t)(b * 49 + n) * 128 + h * 32 + d] = acc[reg];
        if (dt == 0 && lr == 0)
          rs_buf[(size_t)(b * 49 + n) * 4 + h] = accS[reg];
      }
    }
  }
}

// ---------------------------------------------------------------------------
extern "C" void kernel_launch(void* const* d_in, const int* in_sizes, int n_in,
                              void* d_out, int out_size, void* d_ws,
                              size_t ws_size, hipStream_t stream) {
  const float* x = (const float*)d_in[0];
  const float* w_qkv = (const float*)d_in[1];
  const float* b_qkv = (const float*)d_in[2];
  const float* w_off = (const float*)d_in[3];
  const float* b_off = (const float*)d_in[4];
  const float* rpb = (const float*)d_in[5];
  const float* w_proj = (const float*)d_in[6];
  const float* b_proj = (const float*)d_in[7];
  float* out = (float*)d_out;

  float* ws = (float*)d_ws;
  float* qkv_buf = ws;                              // 12544*384
  float* off_buf = qkv_buf + (size_t)MROWS * 384;   // 12544*392
  float* attn_out = off_buf + (size_t)MROWS * 392;  // 12544*128
  float* rs_buf = attn_out + (size_t)MROWS * 128;   // 12544*4

  dwa_gemm<0><<<dim3(196, 13), 256, 0, stream>>>(
      x, w_qkv, w_off, b_qkv, b_off, qkv_buf, off_buf, nullptr);
  dwa_attn<<<BATCH * HEADS, 512, 0, stream>>>(qkv_buf, off_buf, rpb, attn_out,
                                              rs_buf);
  dwa_gemm<1><<<dim3(196, 2), 256, 0, stream>>>(
      attn_out, w_proj, nullptr, b_proj, nullptr, out, nullptr, rs_buf);
}